// Round 6
// baseline (541.444 us; speedup 1.0000x reference)
//
#include <hip/hip_runtime.h>
#include <hip/hip_bf16.h>
#include <stdint.h>

typedef short short8 __attribute__((ext_vector_type(8)));
typedef float f32x4 __attribute__((ext_vector_type(4)));
typedef float f32x2 __attribute__((ext_vector_type(2)));

// ---------- helpers ----------
__device__ __forceinline__ unsigned short f2bf(float x) {
    unsigned u = __float_as_uint(x);
    u += 0x7fffu + ((u >> 16) & 1u);   // RNE
    return (unsigned short)(u >> 16);
}
__device__ __forceinline__ f32x2 up2(unsigned u) {
    f32x2 r;
    r.x = __uint_as_float(u << 16);
    r.y = __uint_as_float(u & 0xffff0000u);
    return r;
}

// ---------- weight prep (+ degree count, fused) ----------
struct WDesc { const float* src; unsigned short* dst; int K, ldd, koff, perm; };
struct WPack { WDesc w[12]; };

__global__ __launch_bounds__(256) void prep_and_count(WPack p,
        const int* __restrict__ d0, int E0, int* c0,
        const int* __restrict__ d1, int E1, int* c1, int nPrep) {
    if ((int)blockIdx.x < nPrep) {
        int wi = blockIdx.x >> 2, chunk = blockIdx.x & 3;
        WDesc d = p.w[wi];
        int total = d.K * 128, cs = total >> 2;
        int lo = chunk * cs, hi = lo + cs;
        for (int i = lo + threadIdx.x; i < hi; i += 256) {
            int n = i / d.K, k = i - n * d.K;
            int kk = d.perm ? (2 * (k & 63) + (k >> 6)) : k;
            d.dst[(size_t)n * d.ldd + d.koff + kk] = f2bf(d.src[(size_t)k * 128 + n]);
        }
    } else {
        int t = (blockIdx.x - nPrep) * 256 + threadIdx.x;
        if (t < E0) atomicAdd(&c0[d0[t]], 1);
        else if (t < E0 + E1) atomicAdd(&c1[d1[t - E0]], 1);
    }
}

// ---------- single-kernel decoupled-lookback scan (both graphs) ----------
__global__ __launch_bounds__(1024) void scan_lookback(
        const int* c0, int N0, int* rp0, int* cur0, int B0, int* flg0,
        const int* c1, int N1, int* rp1, int* cur1, int* flg1) {
    __shared__ int wsum[16];
    __shared__ int pref_s;
    const int* c; int* rp; int* cur; int* flg; int N, blk, B;
    if ((int)blockIdx.x < B0) { c = c0; rp = rp0; cur = cur0; flg = flg0; N = N0; blk = blockIdx.x; B = B0; }
    else { c = c1; rp = rp1; cur = cur1; flg = flg1; N = N1; blk = blockIdx.x - B0; B = gridDim.x - B0; }
    int tid = threadIdx.x, lane = tid & 63, w = tid >> 6;
    int i = blk * 1024 + tid;
    int v = (i < N) ? c[i] : 0;
    int s = v;
#pragma unroll
    for (int off = 1; off < 64; off <<= 1) {
        int t = __shfl_up(s, off, 64);
        if (lane >= off) s += t;
    }
    if (lane == 63) wsum[w] = s;
    __syncthreads();
    if (w == 0 && lane < 16) {
        int ws = wsum[lane];
#pragma unroll
        for (int off = 1; off < 16; off <<= 1) {
            int t = __shfl_up(ws, off, 64);
            if (lane >= off) ws += t;
        }
        wsum[lane] = ws;
    }
    __syncthreads();
    int total = wsum[15];
    if (tid == 0) atomicExch(&flg[blk], total + 1);   // publish (flag = total+1)
    if (w == 0) {
        int mysum = 0;
        if (lane < blk) {
            int t;
            do { t = atomicAdd(&flg[lane], 0); } while (t == 0);
            mysum = t - 1;
        }
#pragma unroll
        for (int o = 1; o < 64; o <<= 1) mysum += __shfl_xor(mysum, o, 64);
        if (lane == 0) pref_s = mysum;
    }
    __syncthreads();
    int prefix = pref_s;
    int wexcl = (w == 0) ? 0 : wsum[w - 1];
    if (i < N) {
        int val = prefix + wexcl + (s - v);
        rp[i] = val;
        cur[i] = val;
    }
    if (blk == B - 1 && tid == 0) rp[N] = prefix + total;
}

// ================= fused GEMM: edge blocks (w/ inline CSR scatter) + node blocks ===
struct NodeOut { const unsigned short* Wt; const float* bias; unsigned int* out; int ldc, coloff; };
struct NodePack { NodeOut d[5]; int nout; };
struct EdgeJob {
    const float* A; const unsigned short* Wt; const float* bias;
    const int* srcI; const int* dstI; int* cursor; int* srcs; unsigned int* out; int M;
};

__global__ __launch_bounds__(256) void gemm_fused(
        EdgeJob e0, EdgeJob e1, int Be0, int BeTot,
        const float* An0, int Mn0, NodePack np0, int Bn0,
        const float* An1, int Mn1, NodePack np1) {
    __shared__ __align__(16) unsigned short sA[64 * 136];
    __shared__ __align__(16) unsigned short sB[128 * 72];
    __shared__ int pos_s[64];

    const int tid = threadIdx.x;
    const int lane = tid & 63, w = tid >> 6;
    const int rb = (w >> 1) * 32, cb = (w & 1) * 64;
    const int qd = lane >> 4, l16 = lane & 15;

    if ((int)blockIdx.x < BeTot) {
        // ---------------- edge path: K=64, inline scatter ----------------
        constexpr int LDA = 72, LDB = 72, TLD = 133;
        EdgeJob p; int blk;
        if ((int)blockIdx.x < Be0) { p = e0; blk = blockIdx.x; }
        else { p = e1; blk = blockIdx.x - Be0; }
        const int rbase = blk * 64;

        if (tid < 64) {
            int t = rbase + tid, pp = 0;
            if (t < p.M) {
                int d = p.dstI[t];
                pp = atomicAdd(&p.cursor[d], 1);
                p.srcs[pp] = p.srcI[t] * 128;   // prescaled kv-row offset
            }
            pos_s[tid] = pp;
        }
        for (int slot = tid; slot < 64 * 8; slot += 256) {
            int row = slot >> 3, kg = slot & 7;
            int gr = rbase + row;
            short8 s8 = {0, 0, 0, 0, 0, 0, 0, 0};
            if (gr < p.M) {
                const float* a = p.A + (size_t)gr * 64 + kg * 8;
                float4 f0 = *reinterpret_cast<const float4*>(a);
                float4 f1 = *reinterpret_cast<const float4*>(a + 4);
                s8[0] = (short)f2bf(f0.x); s8[1] = (short)f2bf(f0.y);
                s8[2] = (short)f2bf(f0.z); s8[3] = (short)f2bf(f0.w);
                s8[4] = (short)f2bf(f1.x); s8[5] = (short)f2bf(f1.y);
                s8[6] = (short)f2bf(f1.z); s8[7] = (short)f2bf(f1.w);
            }
            *reinterpret_cast<short8*>(&sA[row * LDA + kg * 8]) = s8;
        }
        for (int slot = tid; slot < 128 * 8; slot += 256) {
            int n = slot >> 3, kg = slot & 7;
            *reinterpret_cast<short8*>(&sB[n * LDB + kg * 8]) =
                *reinterpret_cast<const short8*>(p.Wt + (size_t)n * 64 + kg * 8);
        }
        __syncthreads();

        f32x4 acc[2][4];
#pragma unroll
        for (int rt = 0; rt < 2; ++rt)
#pragma unroll
            for (int ct = 0; ct < 4; ++ct) { f32x4 z = {0.f,0.f,0.f,0.f}; acc[rt][ct] = z; }
#pragma unroll
        for (int ks = 0; ks < 64; ks += 32) {
            short8 af[2], bfr[4];
#pragma unroll
            for (int rt = 0; rt < 2; ++rt)
                af[rt] = *reinterpret_cast<const short8*>(&sA[(rb + rt * 16 + l16) * LDA + ks + qd * 8]);
#pragma unroll
            for (int ct = 0; ct < 4; ++ct)
                bfr[ct] = *reinterpret_cast<const short8*>(&sB[(cb + ct * 16 + l16) * LDB + ks + qd * 8]);
#pragma unroll
            for (int rt = 0; rt < 2; ++rt)
#pragma unroll
                for (int ct = 0; ct < 4; ++ct)
                    acc[rt][ct] = __builtin_amdgcn_mfma_f32_16x16x32_bf16(
                        af[rt], bfr[ct], acc[rt][ct], 0, 0, 0);
        }

        __syncthreads();
        unsigned short* tile = sB;
#pragma unroll
        for (int ct = 0; ct < 4; ++ct) {
            int col = cb + ct * 16 + l16;
            float bv = p.bias[col];
#pragma unroll
            for (int rt = 0; rt < 2; ++rt)
#pragma unroll
                for (int r = 0; r < 4; ++r)
                    tile[(rb + rt * 16 + qd * 4 + r) * TLD + col] = f2bf(acc[rt][ct][r] + bv);
        }
        __syncthreads();
#pragma unroll
        for (int rep = 0; rep < 4; ++rep) {
            int lrow = (tid >> 4) + rep * 16, seg = tid & 15;
            int gr = rbase + lrow;
            if (gr < p.M) {
                int dpos = pos_s[lrow];
                uint4 pk;
#pragma unroll
                for (int j = 0; j < 4; ++j) {
                    int pcol = seg * 4 + j;
                    unsigned lo16 = tile[lrow * TLD + pcol];
                    unsigned hi16 = tile[lrow * TLD + pcol + 64];
                    ((unsigned*)&pk)[j] = lo16 | (hi16 << 16);
                }
                *reinterpret_cast<uint4*>(&p.out[(size_t)dpos * 64 + seg * 4]) = pk;
            }
        }
    } else {
        // ---------------- node path: K=128, multi-output ----------------
        constexpr int LDA = 136, LDB = 72, TLD = 133;
        int b = blockIdx.x - BeTot;
        const float* A; int M; NodePack dp; int blk;
        if (b < Bn0) { A = An0; M = Mn0; dp = np0; blk = b; }
        else { A = An1; M = Mn1; dp = np1; blk = b - Bn0; }
        const int rbase = blk * 64;

        for (int slot = tid; slot < 64 * 16; slot += 256) {
            int row = slot >> 4, kg = slot & 15;
            int gr = rbase + row;
            short8 s8 = {0, 0, 0, 0, 0, 0, 0, 0};
            if (gr < M) {
                const float* a = A + (size_t)gr * 128 + kg * 8;
                float4 f0 = *reinterpret_cast<const float4*>(a);
                float4 f1 = *reinterpret_cast<const float4*>(a + 4);
                s8[0] = (short)f2bf(f0.x); s8[1] = (short)f2bf(f0.y);
                s8[2] = (short)f2bf(f0.z); s8[3] = (short)f2bf(f0.w);
                s8[4] = (short)f2bf(f1.x); s8[5] = (short)f2bf(f1.y);
                s8[6] = (short)f2bf(f1.z); s8[7] = (short)f2bf(f1.w);
            }
            *reinterpret_cast<short8*>(&sA[row * LDA + kg * 8]) = s8;
        }

        for (int o = 0; o < dp.nout; ++o) {
            NodeOut d = dp.d[o];
            f32x4 acc[2][4];
#pragma unroll
            for (int rt = 0; rt < 2; ++rt)
#pragma unroll
                for (int ct = 0; ct < 4; ++ct) { f32x4 z = {0.f,0.f,0.f,0.f}; acc[rt][ct] = z; }

            for (int kc = 0; kc < 128; kc += 64) {
                __syncthreads();
                for (int slot = tid; slot < 128 * 8; slot += 256) {
                    int n = slot >> 3, kg = slot & 7;
                    *reinterpret_cast<short8*>(&sB[n * LDB + kg * 8]) =
                        *reinterpret_cast<const short8*>(d.Wt + (size_t)n * 128 + kc + kg * 8);
                }
                __syncthreads();
#pragma unroll
                for (int ks = 0; ks < 64; ks += 32) {
                    short8 af[2], bfr[4];
#pragma unroll
                    for (int rt = 0; rt < 2; ++rt)
                        af[rt] = *reinterpret_cast<const short8*>(
                            &sA[(rb + rt * 16 + l16) * LDA + kc + ks + qd * 8]);
#pragma unroll
                    for (int ct = 0; ct < 4; ++ct)
                        bfr[ct] = *reinterpret_cast<const short8*>(
                            &sB[(cb + ct * 16 + l16) * LDB + ks + qd * 8]);
#pragma unroll
                    for (int rt = 0; rt < 2; ++rt)
#pragma unroll
                        for (int ct = 0; ct < 4; ++ct)
                            acc[rt][ct] = __builtin_amdgcn_mfma_f32_16x16x32_bf16(
                                af[rt], bfr[ct], acc[rt][ct], 0, 0, 0);
                }
            }

            __syncthreads();
            unsigned short* tile = sB;
#pragma unroll
            for (int ct = 0; ct < 4; ++ct) {
                int col = cb + ct * 16 + l16;
                float bv = d.bias[col];
#pragma unroll
                for (int rt = 0; rt < 2; ++rt)
#pragma unroll
                    for (int r = 0; r < 4; ++r)
                        tile[(rb + rt * 16 + qd * 4 + r) * TLD + col] = f2bf(acc[rt][ct][r] + bv);
            }
            __syncthreads();
#pragma unroll
            for (int rep = 0; rep < 4; ++rep) {
                int lrow = (tid >> 4) + rep * 16, seg = tid & 15;
                int gr = rbase + lrow;
                if (gr < M) {
                    uint4 pk;
#pragma unroll
                    for (int j = 0; j < 4; ++j) {
                        int pcol = seg * 4 + j;
                        unsigned lo16 = tile[lrow * TLD + pcol];
                        unsigned hi16 = tile[lrow * TLD + pcol + 64];
                        ((unsigned*)&pk)[j] = lo16 | (hi16 << 16);
                    }
                    *reinterpret_cast<uint4*>(&d.out[(size_t)gr * d.ldc + d.coloff + seg * 4]) = pk;
                }
            }
        }
    }
}

// ===== output GEMM: out = LN( [agg|x] @ [Wo;Wnp] + bo + bnp ) =====================
struct OutPack {
    const unsigned short* Aagg; const float* Ax;
    const unsigned short* Wt;   // [128][256]
    const float *bo, *bnp, *g, *bln; float* out; int M;
};

__global__ __launch_bounds__(256) void gemm_out_ln(OutPack p0, OutPack p1, int B0) {
    constexpr int K = 256, LDA = 264, LDB = 72, FTLD = 132;
    __shared__ __align__(16) char smemA[64 * LDA * 2];
    __shared__ __align__(16) unsigned short Bs[128 * LDB];
    unsigned short* As = (unsigned short*)smemA;

    OutPack p; int blk;
    if ((int)blockIdx.x < B0) { p = p0; blk = blockIdx.x; } else { p = p1; blk = blockIdx.x - B0; }

    const int tid = threadIdx.x;
    const int rbase = blk * 64;

    for (int slot = tid; slot < 64 * 32; slot += 256) {
        int row = slot >> 5, kg = slot & 31;
        int gr = rbase + row;
        short8 s8 = {0, 0, 0, 0, 0, 0, 0, 0};
        if (gr < p.M) {
            if (kg < 16) {
                s8 = *reinterpret_cast<const short8*>(p.Aagg + (size_t)gr * 128 + kg * 8);
            } else {
                const float* a = p.Ax + (size_t)gr * 128 + (kg - 16) * 8;
                float4 f0 = *reinterpret_cast<const float4*>(a);
                float4 f1 = *reinterpret_cast<const float4*>(a + 4);
                s8[0] = (short)f2bf(f0.x); s8[1] = (short)f2bf(f0.y);
                s8[2] = (short)f2bf(f0.z); s8[3] = (short)f2bf(f0.w);
                s8[4] = (short)f2bf(f1.x); s8[5] = (short)f2bf(f1.y);
                s8[6] = (short)f2bf(f1.z); s8[7] = (short)f2bf(f1.w);
            }
        }
        *reinterpret_cast<short8*>(&As[row * LDA + kg * 8]) = s8;
    }

    const int lane = tid & 63, w = tid >> 6;
    const int rb = (w >> 1) * 32, cb = (w & 1) * 64;
    const int qd = lane >> 4, l16 = lane & 15;

    f32x4 acc[2][4];
#pragma unroll
    for (int rt = 0; rt < 2; ++rt)
#pragma unroll
        for (int ct = 0; ct < 4; ++ct) { f32x4 z = {0.f,0.f,0.f,0.f}; acc[rt][ct] = z; }

    for (int kc = 0; kc < K; kc += 64) {
        __syncthreads();
        for (int slot = tid; slot < 128 * 8; slot += 256) {
            int n = slot >> 3, kg = slot & 7;
            *reinterpret_cast<short8*>(&Bs[n * LDB + kg * 8]) =
                *reinterpret_cast<const short8*>(p.Wt + (size_t)n * K + kc + kg * 8);
        }
        __syncthreads();
#pragma unroll
        for (int ks = 0; ks < 64; ks += 32) {
            short8 af[2], bfr[4];
#pragma unroll
            for (int rt = 0; rt < 2; ++rt)
                af[rt] = *reinterpret_cast<const short8*>(
                    &As[(rb + rt * 16 + l16) * LDA + kc + ks + qd * 8]);
#pragma unroll
            for (int ct = 0; ct < 4; ++ct)
                bfr[ct] = *reinterpret_cast<const short8*>(
                    &Bs[(cb + ct * 16 + l16) * LDB + ks + qd * 8]);
#pragma unroll
            for (int rt = 0; rt < 2; ++rt)
#pragma unroll
                for (int ct = 0; ct < 4; ++ct)
                    acc[rt][ct] = __builtin_amdgcn_mfma_f32_16x16x32_bf16(
                        af[rt], bfr[ct], acc[rt][ct], 0, 0, 0);
        }
    }

    __syncthreads();
    float* ftile = (float*)smemA;
#pragma unroll
    for (int ct = 0; ct < 4; ++ct) {
        int col = cb + ct * 16 + l16;
        float bv = p.bo[col] + p.bnp[col];
#pragma unroll
        for (int rt = 0; rt < 2; ++rt)
#pragma unroll
            for (int r = 0; r < 4; ++r)
                ftile[(rb + rt * 16 + qd * 4 + r) * FTLD + col] = acc[rt][ct][r] + bv;
    }
    __syncthreads();

    int r = tid >> 2, q4 = tid & 3;
    const float* rowp = &ftile[r * FTLD + q4 * 32];
    float s = 0.f, sq = 0.f;
#pragma unroll
    for (int j = 0; j < 8; ++j) {
        float4 v = *reinterpret_cast<const float4*>(rowp + j * 4);
        s += v.x + v.y + v.z + v.w;
        sq += v.x * v.x + v.y * v.y + v.z * v.z + v.w * v.w;
    }
    s += __shfl_xor(s, 1, 64);  s += __shfl_xor(s, 2, 64);
    sq += __shfl_xor(sq, 1, 64); sq += __shfl_xor(sq, 2, 64);
    float mu = s * (1.f / 128.f);
    float var = sq * (1.f / 128.f) - mu * mu;
    float rs = rsqrtf(var + 1e-5f);
    int gr = rbase + r;
    if (gr < p.M) {
#pragma unroll
        for (int j = 0; j < 8; ++j) {
            float4 v = *reinterpret_cast<const float4*>(rowp + j * 4);
            int c = q4 * 32 + j * 4;
            float4 gg = *reinterpret_cast<const float4*>(p.g + c);
            float4 bb = *reinterpret_cast<const float4*>(p.bln + c);
            float4 o;
            o.x = (v.x - mu) * rs * gg.x + bb.x;
            o.y = (v.y - mu) * rs * gg.y + bb.y;
            o.z = (v.z - mu) * rs * gg.z + bb.z;
            o.w = (v.w - mu) * rs * gg.w + bb.w;
            *reinterpret_cast<float4*>(&p.out[(size_t)gr * 128 + c]) = o;
        }
    }
}

// ================= CSR gather attention: paired cols, f32x2 packed math ===========
struct AttnPack {
    const unsigned int *q, *kv, *e;
    const int *srcs;        // prescaled (src*128), zero-padded past E
    const int *row_ptr;
    unsigned int* agg; int N;
};

__global__ __launch_bounds__(256) void attn_gather(AttnPack a0, AttnPack a1, int B0) {
    AttnPack a; int blk;
    if ((int)blockIdx.x < B0) { a = a0; blk = blockIdx.x; } else { a = a1; blk = blockIdx.x - B0; }
    int dst = blk * 4 + (threadIdx.x >> 6);
    if (dst >= a.N) return;
    int lane = threadIdx.x & 63;

    f32x2 q2 = up2(a.q[(size_t)dst * 64 + lane]);
    int beg = a.row_ptr[dst], end = a.row_ptr[dst + 1];
    f32x2 den = {0.f, 0.f}, acc = {0.f, 0.f};

    int oC = a.srcs[beg];   // padded: safe even when beg==end
    unsigned kC = a.kv[oC + lane];
    unsigned vC = a.kv[oC + 64 + lane];
    unsigned eC = a.e[(size_t)beg * 64 + lane];

    for (int i = beg; i < end; ++i) {
        int oN = a.srcs[i + 1];
        unsigned kN = a.kv[oN + lane];
        unsigned vN = a.kv[oN + 64 + lane];
        unsigned eN = a.e[(size_t)(i + 1) * 64 + lane];

        f32x2 kk = up2(kC), vv = up2(vC), ee = up2(eC);
        f32x2 ke = kk + ee;
        float pl = q2.x * ke.x, ph = q2.y * ke.y;
#pragma unroll
        for (int m = 1; m < 16; m <<= 1) {
            pl += __shfl_xor(pl, m, 64);
            ph += __shfl_xor(ph, m, 64);
        }
        f32x2 ex;
        ex.x = __expf(pl * 0.25f);
        ex.y = __expf(ph * 0.25f);
        den += ex;
        acc += ex * (vv + ee);
        kC = kN; vC = vN; eC = eN;
    }
    float ol = den.x > 0.f ? acc.x / den.x : 0.f;
    float oh = den.y > 0.f ? acc.y / den.y : 0.f;
    a.agg[(size_t)dst * 64 + lane] = (unsigned)f2bf(ol) | ((unsigned)f2bf(oh) << 16);
}

extern "C" void kernel_launch(void* const* d_in, const int* in_sizes, int n_in,
                              void* d_out, int out_size, void* d_ws, size_t ws_size,
                              hipStream_t stream) {
    const float* x_pc  = (const float*)d_in[0];
    const float* x_gr  = (const float*)d_in[1];
    const float* ea_pp = (const float*)d_in[2];
    const float* ea_pg = (const float*)d_in[3];
    const int* ei_pp   = (const int*)d_in[4];
    const int* ei_pg   = (const int*)d_in[5];
    const float *Wq_pp = (const float*)d_in[6],  *bq_pp = (const float*)d_in[7];
    const float *Wk_pp = (const float*)d_in[8],  *bk_pp = (const float*)d_in[9];
    const float *Wv_pp = (const float*)d_in[10], *bv_pp = (const float*)d_in[11];
    const float *We_pp = (const float*)d_in[12], *be_pp = (const float*)d_in[13];
    const float *Wo_pp = (const float*)d_in[14], *bo_pp = (const float*)d_in[15];
    const float *Wq_pg = (const float*)d_in[16], *bq_pg = (const float*)d_in[17];
    const float *Wk_pg = (const float*)d_in[18], *bk_pg = (const float*)d_in[19];
    const float *Wv_pg = (const float*)d_in[20], *bv_pg = (const float*)d_in[21];
    const float *We_pg = (const float*)d_in[22], *be_pg = (const float*)d_in[23];
    const float *Wo_pg = (const float*)d_in[24], *bo_pg = (const float*)d_in[25];
    const float *Wnp_pc = (const float*)d_in[26], *bnp_pc = (const float*)d_in[27];
    const float *g_pc   = (const float*)d_in[28], *bln_pc = (const float*)d_in[29];
    const float *Wnp_gr = (const float*)d_in[30], *bnp_gr = (const float*)d_in[31];
    const float *g_gr   = (const float*)d_in[32], *bln_gr = (const float*)d_in[33];

    const int N_pc = in_sizes[0] / 128;
    const int N_gr = in_sizes[1] / 128;
    const int E_pp = in_sizes[4] / 2;
    const int E_pg = in_sizes[5] / 2;

    char* ws = (char*)d_ws;
    size_t off = 0;
    auto alloc = [&](size_t bytes) -> char* {
        char* p = ws + off;
        off += (bytes + 255) & ~(size_t)255;
        return p;
    };
    unsigned short* Wt_q_pp = (unsigned short*)alloc(128 * 128 * 2);
    unsigned short* Wt_k_pp = (unsigned short*)alloc(128 * 128 * 2);
    unsigned short* Wt_v_pp = (unsigned short*)alloc(128 * 128 * 2);
    unsigned short* Wt_k_pg = (unsigned short*)alloc(128 * 128 * 2);
    unsigned short* Wt_v_pg = (unsigned short*)alloc(128 * 128 * 2);
    unsigned short* Wt_q_pg = (unsigned short*)alloc(128 * 128 * 2);
    unsigned short* Wt_e_pp = (unsigned short*)alloc(64 * 128 * 2);
    unsigned short* Wt_e_pg = (unsigned short*)alloc(64 * 128 * 2);
    unsigned short* Wt_cat_pp = (unsigned short*)alloc(256 * 128 * 2);
    unsigned short* Wt_cat_gr = (unsigned short*)alloc(256 * 128 * 2);

    unsigned int* q_pp  = (unsigned int*)alloc((size_t)N_pc * 64 * 4);
    unsigned int* kv_pp = (unsigned int*)alloc((size_t)N_pc * 128 * 4);
    unsigned int* q_pg  = (unsigned int*)alloc((size_t)N_gr * 64 * 4);
    unsigned int* kv_pg = (unsigned int*)alloc((size_t)N_pc * 128 * 4);
    unsigned int* e_pp  = (unsigned int*)alloc((size_t)(E_pp + 1) * 64 * 4);
    unsigned int* e_pg  = (unsigned int*)alloc((size_t)(E_pg + 1) * 64 * 4);
    unsigned int* agg_pp = (unsigned int*)alloc((size_t)N_pc * 64 * 4);
    unsigned int* agg_pg = (unsigned int*)alloc((size_t)N_gr * 64 * 4);
    int* row_ptr_pp = (int*)alloc((size_t)(N_pc + 1) * 4);
    int* cursor_pp  = (int*)alloc((size_t)N_pc * 4);
    int* row_ptr_pg = (int*)alloc((size_t)(N_gr + 1) * 4);
    int* cursor_pg  = (int*)alloc((size_t)N_gr * 4);
    char* zbase = ws + off;   // zero region: counts + flags + padded srcs
    int* counts_pp = (int*)alloc((size_t)N_pc * 4);
    int* counts_pg = (int*)alloc((size_t)N_gr * 4);
    int* flg_pp    = (int*)alloc(64 * 4);
    int* flg_pg    = (int*)alloc(64 * 4);
    int* srcs_pp   = (int*)alloc((size_t)(E_pp + 8) * 4);
    int* srcs_pg   = (int*)alloc((size_t)(E_pg + 8) * 4);
    size_t zbytes = (size_t)((ws + off) - zbase);
    hipMemsetAsync(zbase, 0, zbytes, stream);

    float* out_pc = (float*)d_out;
    float* out_gr = out_pc + (size_t)N_pc * 128;

    const int* src_pp = ei_pp;
    const int* dst_pp = ei_pp + E_pp;
    const int* src_pg = ei_pg;
    const int* dst_pg = ei_pg + E_pg;

    // ---- weight prep + degree count (one launch) ----
    WPack wp;
    wp.w[0]  = {Wq_pp, Wt_q_pp, 128, 128, 0, 0};
    wp.w[1]  = {Wk_pp, Wt_k_pp, 128, 128, 0, 0};
    wp.w[2]  = {Wv_pp, Wt_v_pp, 128, 128, 0, 0};
    wp.w[3]  = {Wk_pg, Wt_k_pg, 128, 128, 0, 0};
    wp.w[4]  = {Wv_pg, Wt_v_pg, 128, 128, 0, 0};
    wp.w[5]  = {Wq_pg, Wt_q_pg, 128, 128, 0, 0};
    wp.w[6]  = {We_pp, Wt_e_pp, 64, 64, 0, 0};
    wp.w[7]  = {We_pg, Wt_e_pg, 64, 64, 0, 0};
    wp.w[8]  = {Wo_pp, Wt_cat_pp, 128, 256, 0, 1};
    wp.w[9]  = {Wnp_pc, Wt_cat_pp, 128, 256, 128, 0};
    wp.w[10] = {Wo_pg, Wt_cat_gr, 128, 256, 0, 1};
    wp.w[11] = {Wnp_gr, Wt_cat_gr, 128, 256, 128, 0};
    const int NPREP = 48;
    const int gE = (E_pp + E_pg + 255) / 256;
    prep_and_count<<<NPREP + gE, 256, 0, stream>>>(wp, dst_pp, E_pp, counts_pp,
                                                   dst_pg, E_pg, counts_pg, NPREP);

    // ---- CSR scan (one kernel, decoupled lookback) ----
    const int Bs_pp = (N_pc + 1023) / 1024, Bs_pg = (N_gr + 1023) / 1024;
    scan_lookback<<<Bs_pp + Bs_pg, 1024, 0, stream>>>(
        counts_pp, N_pc, row_ptr_pp, cursor_pp, Bs_pp, flg_pp,
        counts_pg, N_gr, row_ptr_pg, cursor_pg, flg_pg);

    // ---- fused GEMM: edge (w/ inline scatter) + node projections ----
    EdgeJob ej0 = {ea_pp, Wt_e_pp, be_pp, src_pp, dst_pp, cursor_pp, srcs_pp, e_pp, E_pp};
    EdgeJob ej1 = {ea_pg, Wt_e_pg, be_pg, src_pg, dst_pg, cursor_pg, srcs_pg, e_pg, E_pg};
    int Be0 = (E_pp + 63) / 64, Be1 = (E_pg + 63) / 64;
    NodePack np;
    np.d[0] = {Wt_q_pp, bq_pp, q_pp, 64, 0};
    np.d[1] = {Wt_k_pp, bk_pp, kv_pp, 128, 0};
    np.d[2] = {Wt_v_pp, bv_pp, kv_pp, 128, 64};
    np.d[3] = {Wt_k_pg, bk_pg, kv_pg, 128, 0};
    np.d[4] = {Wt_v_pg, bv_pg, kv_pg, 128, 64};
    np.nout = 5;
    NodePack ng{};
    ng.d[0] = {Wt_q_pg, bq_pg, q_pg, 64, 0};
    ng.nout = 1;
    int Bn0 = (N_pc + 63) / 64, Bn1 = (N_gr + 63) / 64;
    gemm_fused<<<Be0 + Be1 + Bn0 + Bn1, 256, 0, stream>>>(
        ej0, ej1, Be0, Be0 + Be1, x_pc, N_pc, np, Bn0, x_gr, N_gr, ng);

    // ---- gather attention ----
    AttnPack ap0 = {q_pp, kv_pp, e_pp, srcs_pp, row_ptr_pp, agg_pp, N_pc};
    AttnPack ap1 = {q_pg, kv_pg, e_pg, srcs_pg, row_ptr_pg, agg_pg, N_gr};
    int Ba0 = (N_pc + 3) / 4, Ba1 = (N_gr + 3) / 4;
    attn_gather<<<Ba0 + Ba1, 256, 0, stream>>>(ap0, ap1, Ba0);

    // ---- output GEMM + residual + LayerNorm ----
    OutPack op0 = {(const unsigned short*)agg_pp, x_pc, Wt_cat_pp, bo_pp, bnp_pc, g_pc, bln_pc, out_pc, N_pc};
    OutPack op1 = {(const unsigned short*)agg_pg, x_gr, Wt_cat_gr, bo_pg, bnp_gr, g_gr, bln_gr, out_gr, N_gr};
    int Bo0 = (N_pc + 63) / 64, Bo1 = (N_gr + 63) / 64;
    gemm_out_ln<<<Bo0 + Bo1, 256, 0, stream>>>(op0, op1, Bo0);
}